// Round 7
// baseline (308.594 us; speedup 1.0000x reference)
//
#include <hip/hip_runtime.h>
#include <math.h>

// Problem constants (B,S,D,H) = (4,2048,1024,16), HD=64
#define BATCH 4
#define SEQ   2048
#define DMODEL 1024
#define NHEAD 16
#define HDIM  64
#define MROWS (BATCH*SEQ)   // 8192

typedef unsigned short u16;
typedef unsigned int   u32;

using bf16x8 = __attribute__((ext_vector_type(8))) short;
using f32x4  = __attribute__((ext_vector_type(4))) float;
using f32x16 = __attribute__((ext_vector_type(16))) float;

__device__ __forceinline__ u16 f2bf(float f) {
    u32 u = __float_as_uint(f);
    u += 0x7fffu + ((u >> 16) & 1u);
    return (u16)(u >> 16);
}
__device__ __forceinline__ u32 pack2bf(float a, float b) {
    u32 ua = __float_as_uint(a); ua += 0x7fffu + ((ua >> 16) & 1u);
    u32 ub = __float_as_uint(b); ub += 0x7fffu + ((ub >> 16) & 1u);
    return (ua >> 16) | (ub & 0xffff0000u);
}

// async global->LDS, 16 B per lane; LDS dest = wave-uniform base + lane*16
#define GLOBAL_LOAD_LDS16(gp, lp)                                              \
    __builtin_amdgcn_global_load_lds(                                          \
        (const __attribute__((address_space(1))) void*)(gp),                   \
        (__attribute__((address_space(3))) void*)(lp), 16, 0, 0)

// ---------------------------------------------------------------------------
// Convert x (8.4M) + Wq/Wk/Wv/Wo (1M each) fp32 -> bf16 into contiguous dst.
// ---------------------------------------------------------------------------
__global__ __launch_bounds__(256) void convert_inputs(
    const float* __restrict__ x,  const float* __restrict__ wq,
    const float* __restrict__ wk, const float* __restrict__ wv,
    const float* __restrict__ wo, u16* __restrict__ dst)
{
    long long i4 = ((long long)blockIdx.x * 256 + threadIdx.x) * 4;
    const float* src; long long off;
    if (i4 < 8388608LL) { src = x; off = i4; }
    else {
        long long j = i4 - 8388608LL;
        int seg = (int)(j >> 20);
        off = j & 1048575LL;
        src = (seg == 0) ? wq : (seg == 1) ? wk : (seg == 2) ? wv : wo;
    }
    float4 v = *(const float4*)(src + off);
    u32 lo = (u32)f2bf(v.x) | ((u32)f2bf(v.y) << 16);
    u32 hi = (u32)f2bf(v.z) | ((u32)f2bf(v.w) << 16);
    *(uint2*)(dst + i4) = make_uint2(lo, hi);
}

// ---------------------------------------------------------------------------
// QKV bf16 MFMA GEMM: C[M,N] = A @ W^T + bias.  128x128 tile, BK=32.
// global_load_lds staging; 64-B LDS rows, swizzle key = (row>>1)&3
// (conflict-free b128 frag reads, verified: 6.29M -> 0 conflicts).
// XCD-aware mapping (xcd = bx&7): 2 MB of A stays L2-resident per XCD.
// seg 0/1/2 = Q/K/V; epilogue RoPE(+0.125*log2e) / RoPE / plain bf16.
// ---------------------------------------------------------------------------
__global__ __launch_bounds__(256) void gemm_qkv(
    const u16* __restrict__ A,
    const u16* __restrict__ Wq_, const u16* __restrict__ Wk_, const u16* __restrict__ Wv_,
    const float* __restrict__ bq_, const float* __restrict__ bk_, const float* __restrict__ bv_,
    u16* __restrict__ Cq_, u16* __restrict__ Ck_, u16* __restrict__ Cv_)
{
    __shared__ u16 As[128 * 32];
    __shared__ u16 Ws[128 * 32];

    const int t    = threadIdx.x;
    const int lane = t & 63;
    const int w    = t >> 6;
    const int quad = lane >> 4;
    const int l15  = lane & 15;

    const int bx  = blockIdx.x;
    const int xcd = bx & 7;
    const int i_  = bx >> 3;
    const int bml = i_ & 7;
    const int n_  = (i_ >> 3) & 7;
    const int seg = i_ >> 6;

    const u16*   W    = (seg == 0) ? Wq_ : (seg == 1) ? Wk_ : Wv_;
    const float* bias = (seg == 0) ? bq_ : (seg == 1) ? bk_ : bv_;
    u16*         Cb   = (seg == 0) ? Cq_ : (seg == 1) ? Ck_ : Cv_;

    const int bm   = (xcd * 8 + bml) * 128;
    const int bn   = n_ * 128;
    const int wrow = (w & 1) * 64;
    const int wcol = (w >> 1) * 64;

    const int srl = lane >> 2;
    const int sc  = (lane & 3) ^ ((lane >> 3) & 3);

    f32x4 acc[4][4] = {};

    for (int k0 = 0; k0 < DMODEL; k0 += 32) {
        __syncthreads();
        #pragma unroll
        for (int i = 0; i < 2; i++) {
            int row = 32 * w + 16 * i + srl;
            GLOBAL_LOAD_LDS16(A + (size_t)(bm + row) * DMODEL + k0 + sc * 8,
                              &As[(32 * w + 16 * i) * 32]);
            GLOBAL_LOAD_LDS16(W + (size_t)(bn + row) * DMODEL + k0 + sc * 8,
                              &Ws[(32 * w + 16 * i) * 32]);
        }
        __syncthreads();

        bf16x8 af[4], bfr[4];
        const int pc = quad ^ ((l15 >> 1) & 3);
        #pragma unroll
        for (int i = 0; i < 4; i++)
            af[i] = *(const bf16x8*)&As[(wrow + 16 * i + l15) * 32 + pc * 8];
        #pragma unroll
        for (int j = 0; j < 4; j++)
            bfr[j] = *(const bf16x8*)&Ws[(wcol + 16 * j + l15) * 32 + pc * 8];
        #pragma unroll
        for (int i = 0; i < 4; i++)
            #pragma unroll
            for (int j = 0; j < 4; j++)
                acc[i][j] = __builtin_amdgcn_mfma_f32_16x16x32_bf16(af[i], bfr[j], acc[i][j], 0, 0, 0);
    }

    float bv[4];
    #pragma unroll
    for (int j = 0; j < 4; j++) bv[j] = bias[bn + wcol + 16 * j + l15];

    if (seg == 2) {
        #pragma unroll
        for (int i = 0; i < 4; i++)
            #pragma unroll
            for (int r = 0; r < 4; r++) {
                int mg = bm + wrow + 16 * i + quad * 4 + r;
                #pragma unroll
                for (int j = 0; j < 4; j++)
                    Cb[(size_t)mg * DMODEL + bn + wcol + 16 * j + l15] = f2bf(acc[i][j][r] + bv[j]);
            }
    } else {
        // RoPE: wave's 64-col span = one head; pair (d, d+32) = j-tiles (j, j+2)
        // Q additionally scaled by 0.125*log2(e) so attention uses exp2.
        const float qscale = (seg == 0) ? 0.18033688011112042f : 1.0f;
        float inv[2];
        #pragma unroll
        for (int j = 0; j < 2; j++) {
            int d = 16 * j + l15;                              // 0..31
            inv[j] = exp2f(-(float)d * 0.4152410118609203f);   // 10000^(-d/32)
        }
        #pragma unroll
        for (int i = 0; i < 4; i++)
            #pragma unroll
            for (int r = 0; r < 4; r++) {
                int mg = bm + wrow + 16 * i + quad * 4 + r;
                int s  = mg & (SEQ - 1);
                #pragma unroll
                for (int j = 0; j < 2; j++) {
                    float f = (float)s * inv[j];
                    float sn, cs;
                    __sincosf(f, &sn, &cs);
                    float a1 = acc[i][j][r]     + bv[j];
                    float a2 = acc[i][j + 2][r] + bv[j + 2];
                    float o1 = (a1 * cs - a2 * sn) * qscale;
                    float o2 = (a2 * cs + a1 * sn) * qscale;
                    Cb[(size_t)mg * DMODEL + bn + wcol + 16 * j       + l15] = f2bf(o1);
                    Cb[(size_t)mg * DMODEL + bn + wcol + 16 * (j + 2) + l15] = f2bf(o2);
                }
            }
    }
}

// ---------------------------------------------------------------------------
// Output projection: C[M,N] = A @ Wo^T + bias (fp32 out). 64x128 tiles ->
// 1024 blocks (4/CU resident; the 512-block 128x128 version exposed the
// staging barrier drain at 2 blocks/CU -> ~95 us). LDS 12 KB.
// ---------------------------------------------------------------------------
__global__ __launch_bounds__(256) void gemm_out(
    const u16* __restrict__ A, const u16* __restrict__ W,
    const float* __restrict__ bias, float* __restrict__ C)
{
    __shared__ u16 As[64 * 32];
    __shared__ u16 Ws[128 * 32];

    const int t    = threadIdx.x;
    const int lane = t & 63;
    const int w    = t >> 6;
    const int quad = lane >> 4;
    const int l15  = lane & 15;

    const int bx  = blockIdx.x;
    const int xcd = bx & 7;
    const int i_  = bx >> 3;
    const int bml = i_ & 15;       // 16 m-tiles of 64 rows per XCD
    const int n_  = i_ >> 4;       // 0..7

    const int bm   = (xcd * 16 + bml) * 64;
    const int bn   = n_ * 128;
    const int wrow = (w & 1) * 32;
    const int wcol = (w >> 1) * 64;

    const int srl = lane >> 2;
    const int sc  = (lane & 3) ^ ((lane >> 3) & 3);

    f32x4 acc[2][4] = {};

    for (int k0 = 0; k0 < DMODEL; k0 += 32) {
        __syncthreads();
        GLOBAL_LOAD_LDS16(A + (size_t)(bm + 16 * w + srl) * DMODEL + k0 + sc * 8,
                          &As[(16 * w) * 32]);
        #pragma unroll
        for (int i = 0; i < 2; i++) {
            int row = 32 * w + 16 * i + srl;
            GLOBAL_LOAD_LDS16(W + (size_t)(bn + row) * DMODEL + k0 + sc * 8,
                              &Ws[(32 * w + 16 * i) * 32]);
        }
        __syncthreads();

        bf16x8 af[2], bfr[4];
        const int pc = quad ^ ((l15 >> 1) & 3);
        #pragma unroll
        for (int i = 0; i < 2; i++)
            af[i] = *(const bf16x8*)&As[(wrow + 16 * i + l15) * 32 + pc * 8];
        #pragma unroll
        for (int j = 0; j < 4; j++)
            bfr[j] = *(const bf16x8*)&Ws[(wcol + 16 * j + l15) * 32 + pc * 8];
        #pragma unroll
        for (int i = 0; i < 2; i++)
            #pragma unroll
            for (int j = 0; j < 4; j++)
                acc[i][j] = __builtin_amdgcn_mfma_f32_16x16x32_bf16(af[i], bfr[j], acc[i][j], 0, 0, 0);
    }

    float bv[4];
    #pragma unroll
    for (int j = 0; j < 4; j++) bv[j] = bias[bn + wcol + 16 * j + l15];
    #pragma unroll
    for (int i = 0; i < 2; i++)
        #pragma unroll
        for (int r = 0; r < 4; r++) {
            int mg = bm + wrow + 16 * i + quad * 4 + r;
            #pragma unroll
            for (int j = 0; j < 4; j++)
                C[(size_t)mg * DMODEL + bn + wcol + 16 * j + l15] = acc[i][j][r] + bv[j];
        }
}

// ---------------------------------------------------------------------------
// MFMA flash attention v4: 32x32x16, 128 q-rows/block, 4 waves, max-free
// exp2 softmax.  P built ENTIRELY in registers: S^T C-layout and PV A-layout
// share q = lane&31; cross-half (lane^32) shfl supplies the other k-run.
// Vt staging conflict-free (u=t>>3, v=t&7; swizzle key (row^(row>>3))&7).
// Qs (16 KB) overlaid by Ks+Vt after fragment hoist -> 16.9 KB LDS total.
// ---------------------------------------------------------------------------
__global__ __launch_bounds__(256, 4) void attn_mfma(
    const u16* __restrict__ Q, const u16* __restrict__ K,
    const u16* __restrict__ V, u16* __restrict__ O)
{
    __shared__ u16 Qs[128 * 64];     // after hoist: Ks = Qs[0..], Vt = Qs[4096..]
    __shared__ float lS[128];
    u16* const Ks = Qs;
    u16* const Vt = Qs + 64 * 64;

    const int t    = threadIdx.x;
    const int lane = t & 63;
    const int w    = t >> 6;            // wave owns q rows [32w, 32w+32)
    const int l31  = lane & 31;
    const int hl   = lane >> 5;         // 0/1
    const int bid  = blockIdx.x;
    const int bh   = bid & 63;
    const int qt   = 15 - (bid >> 6);   // heavy q-tiles first (grid 1024)
    const int h    = bh & (NHEAD - 1);
    const int b    = bh >> 4;
    const int q0   = qt * 128;

    const size_t gbase = ((size_t)b * SEQ) * DMODEL + h * HDIM;

    const int rl = lane >> 3, cp = lane & 7;   // staging row / phys chunk

    // ---- stage Q (128 rows); source chunk = phys ^ key(row), key=(row^(row>>3))&7
    #pragma unroll
    for (int i = 0; i < 4; i++) {
        int row = 32 * w + 8 * i + rl;              // row>>3 = 4w+i, row&7 = rl
        int c   = cp ^ rl ^ ((4 * w + i) & 7);
        GLOBAL_LOAD_LDS16(Q + gbase + (size_t)(q0 + row) * DMODEL + c * 8,
                          &Qs[(32 * w + 8 * i) * 64]);
    }
    __syncthreads();

    // ---- hoist Q B-fragments: B[k][n=q], chunk logical (hl+2s)
    const int qrow = 32 * w + l31;
    const int qg   = q0 + qrow;
    bf16x8 qf[4];
    #pragma unroll
    for (int s = 0; s < 4; s++) {
        int c = (hl + 2 * s) ^ ((qrow ^ (qrow >> 3)) & 7);
        qf[s] = *(const bf16x8*)&Qs[qrow * 64 + c * 8];
    }
    __syncthreads();   // hoists done before Ks/Vt overwrite Qs

    float lsum = 0.0f;
    f32x16 oacc[2] = {};

    const int ktn = 2 * qt + 2;
    for (int kt = 0; kt < ktn; kt++) {
        const int k0 = kt * 64;

        // ---- stage K (64 rows): per wave 16 rows, 2 issues
        #pragma unroll
        for (int i = 0; i < 2; i++) {
            int row = 16 * w + 8 * i + rl;          // row>>3 = 2w+i
            int c   = cp ^ rl ^ ((2 * w + i) & 7);
            GLOBAL_LOAD_LDS16(K + gbase + (size_t)(k0 + row) * DMODEL + c * 8,
                              &Ks[(16 * w + 8 * i) * 64]);
        }
        // ---- stage V transposed, conflict-free: thread (u=t>>3, v=t&7)
        //      loads rows 2u,2u+1 at d-chunk v; writes pairs at word u.
        {
            int u = t >> 3, v = t & 7;
            int j0 = 2 * u;
            uint4 va = *(const uint4*)(V + gbase + (size_t)(k0 + j0)     * DMODEL + 8 * v);
            uint4 vb = *(const uint4*)(V + gbase + (size_t)(k0 + j0 + 1) * DMODEL + 8 * v);
            const u16* pa = (const u16*)&va;
            const u16* pb = (const u16*)&vb;
            #pragma unroll
            for (int e = 0; e < 8; e++) {
                int row = 8 * v + e;                 // key = e ^ v
                int pch = (u >> 2) ^ e ^ v;
                *(u32*)&Vt[row * 64 + pch * 8 + (u & 3) * 2] =
                    (u32)pa[e] | ((u32)pb[e] << 16);
            }
        }
        __syncthreads();

        #pragma unroll
        for (int krh = 0; krh < 2; krh++) {
            const int kcb = k0 + 32 * krh;
            if (kcb > q0 + 32 * w + 31) continue;   // wave-uniform: fully masked

            // ---- S^T quadrant: D[m=kr][n=q]
            f32x16 s = {};
            #pragma unroll
            for (int stp = 0; stp < 4; stp++) {
                int row = 32 * krh + l31;
                int c   = (hl + 2 * stp) ^ ((row ^ (row >> 3)) & 7);
                bf16x8 ka = *(const bf16x8*)&Ks[row * 64 + c * 8];
                s = __builtin_amdgcn_mfma_f32_32x32x16_bf16(ka, qf[stp], s, 0, 0, 0);
            }
            // causal mask on diagonal-crossing quadrants
            if (kcb + 31 > q0 + 32 * w) {
                #pragma unroll
                for (int r = 0; r < 16; r++) {
                    int krg = kcb + (r & 3) + 8 * (r >> 2) + 4 * hl;
                    if (krg > qg) s[r] = -1e30f;
                }
            }
            // ---- exp2 (max-free), l accumulate, pack into 4 runs of 2 u32
            float pv[16];
            #pragma unroll
            for (int r = 0; r < 16; r++) { pv[r] = exp2f(s[r]); lsum += pv[r]; }
            u32 pr[4][2];
            #pragma unroll
            for (int rho = 0; rho < 4; rho++)
                #pragma unroll
                for (int p = 0; p < 2; p++)
                    pr[rho][p] = pack2bf(pv[4 * rho + 2 * p], pv[4 * rho + 2 * p + 1]);

            // ---- PV: build A-frag in regs (self run + partner run via shfl)
            #pragma unroll
            for (int sh = 0; sh < 2; sh++) {
                int sg = 2 * krh + sh;
                u32 self0 = pr[2 * sh + hl][0],        self1 = pr[2 * sh + hl][1];
                u32 pub0  = pr[2 * sh + (hl ^ 1)][0],  pub1  = pr[2 * sh + (hl ^ 1)][1];
                u32 got0 = (u32)__shfl_xor((int)pub0, 32, 64);
                u32 got1 = (u32)__shfl_xor((int)pub1, 32, 64);
                union { u32 u[4]; bf16x8 v; } pf;
                pf.u[0] = hl ? got0 : self0;
                pf.u[1] = hl ? got1 : self1;
                pf.u[2] = hl ? self0 : got0;
                pf.u[3] = hl ? self1 : got1;
                #pragma unroll
                for (int dh = 0; dh < 2; dh++) {
                    int vrow = 32 * dh + l31;
                    int c    = (hl + 2 * sg) ^ ((vrow ^ (vrow >> 3)) & 7);
                    bf16x8 vf = *(const bf16x8*)&Vt[vrow * 64 + c * 8];
                    oacc[dh] = __builtin_amdgcn_mfma_f32_32x32x16_bf16(pf.v, vf, oacc[dh], 0, 0, 0);
                }
            }
        }
        __syncthreads();   // compute done before next stage overwrites Ks/Vt
    }

    // ---- finalize l (cross-half reduce, through LDS to reindex by q)
    lsum += __shfl_xor(lsum, 32, 64);
    if (hl == 0) lS[32 * w + l31] = lsum;
    __syncthreads();

    // ---- writeout: O / l  (C layout: col=l31=d-local, row=(r&3)+8(r>>2)+4hl)
    #pragma unroll
    for (int g = 0; g < 4; g++) {
        f32x4 lv = *(const f32x4*)&lS[32 * w + 8 * g + 4 * hl];
        #pragma unroll
        for (int rr = 0; rr < 4; rr++) {
            int qgw = q0 + 32 * w + rr + 8 * g + 4 * hl;
            float inv = 1.0f / lv[rr];
            #pragma unroll
            for (int dh = 0; dh < 2; dh++) {
                float o = oacc[dh][4 * g + rr] * inv;
                O[gbase + (size_t)qgw * DMODEL + 32 * dh + l31] = f2bf(o);
            }
        }
    }
}

// ---------------------------------------------------------------------------
extern "C" void kernel_launch(void* const* d_in, const int* in_sizes, int n_in,
                              void* d_out, int out_size, void* d_ws, size_t ws_size,
                              hipStream_t stream)
{
    const float* x  = (const float*)d_in[0];
    const float* Wq = (const float*)d_in[1];
    const float* bq = (const float*)d_in[2];
    const float* Wk = (const float*)d_in[3];
    const float* bk = (const float*)d_in[4];
    const float* Wv = (const float*)d_in[5];
    const float* bv = (const float*)d_in[6];
    const float* Wo = (const float*)d_in[7];
    const float* bo = (const float*)d_in[8];

    u16* wsp = (u16*)d_ws;
    u16* xb  = wsp;                    // 8388608
    u16* Wqb = wsp + 8388608;          // 1048576 each
    u16* Wkb = Wqb + 1048576;
    u16* Wvb = Wkb + 1048576;
    u16* Wob = Wvb + 1048576;
    u16* Qb  = Wob + 1048576;          // 8388608 each
    u16* Kb  = Qb + 8388608;
    u16* Vb  = Kb + 8388608;
    u16* Ab  = Vb + 8388608;

    convert_inputs<<<12288, 256, 0, stream>>>(x, Wq, Wk, Wv, Wo, xb);

    gemm_qkv<<<1536, 256, 0, stream>>>(xb, Wqb, Wkb, Wvb, bq, bk, bv, Qb, Kb, Vb);

    attn_mfma<<<1024, 256, 0, stream>>>(Qb, Kb, Vb, Ab);

    gemm_out<<<1024, 256, 0, stream>>>(Ab, Wob, bo, (float*)d_out);
}